// Round 1
// baseline (1118.872 us; speedup 1.0000x reference)
//
#include <hip/hip_runtime.h>

// ---------------------------------------------------------------------------
// MultiScaleRetention forward, MI355X/gfx950.
// B=1, T=4096, E=1024, VD=2048, H=8, KD=128, HD=256.
// Strategy: bf16 MFMA (32x32x16) for all GEMM-shaped work; decay mask computed
// analytically (inner_mask input ignored: 512MB of pure exp(log g * (t-s))).
// den = clip(sum|S|,1,5e4) is post-hoc: accumulate unnormalized O and den,
// divide in epilogue. Causal tiling + per-head decay-underflow skip.
// ---------------------------------------------------------------------------

typedef __attribute__((ext_vector_type(8)))  short  short8;
typedef __attribute__((ext_vector_type(16))) float  floatx16;

__device__ inline unsigned short f2bf(float f){
  unsigned int u = __builtin_bit_cast(unsigned int, f);
  unsigned int r = (u + 0x7fffu + ((u >> 16) & 1u)) >> 16;   // RNE
  return (unsigned short)r;
}
__device__ inline float bf2f(unsigned short u){
  unsigned int x = ((unsigned int)u) << 16;
  return __builtin_bit_cast(float, x);
}
__device__ inline void async_cp16(const void* g, const void* l){
  __builtin_amdgcn_global_load_lds((const __attribute__((address_space(1))) void*)g,
                                   (__attribute__((address_space(3))) void*)l, 16, 0, 0);
}

// ---------------- x -> bf16 -------------------------------------------------
struct us4 { unsigned short a,b,c,d; };
__global__ void k_cvt_x(const float* __restrict__ x, unsigned short* __restrict__ xb, int n4){
  int i = blockIdx.x*blockDim.x + threadIdx.x;
  if (i >= n4) return;
  float4 v = ((const float4*)x)[i];
  us4 o = { f2bf(v.x), f2bf(v.y), f2bf(v.z), f2bf(v.w) };
  ((us4*)xb)[i] = o;
}

// ---------------- fp32 (R,C) -> bf16 (C,R) transpose ------------------------
__global__ __launch_bounds__(256) void k_transpose_f2b(const float* __restrict__ src,
    unsigned short* __restrict__ dst, int R, int C){
  __shared__ float tile[64][65];
  int c0 = blockIdx.x*64, r0 = blockIdx.y*64;
  #pragma unroll
  for (int i=0;i<16;++i){
    int idx = i*256 + threadIdx.x; int r = idx>>6, c = idx&63;
    tile[r][c] = src[(size_t)(r0+r)*C + c0 + c];
  }
  __syncthreads();
  #pragma unroll
  for (int i=0;i<16;++i){
    int idx = i*256 + threadIdx.x; int r = idx>>6, c = idx&63;
    dst[(size_t)(c0+r)*R + r0 + c] = f2bf(tile[c][r]);
  }
}

// ---------------- bf16 (R,C) -> bf16 (C,R) transpose ------------------------
__global__ __launch_bounds__(256) void k_transpose_b2b(const unsigned short* __restrict__ src,
    unsigned short* __restrict__ dst, int R, int C){
  __shared__ unsigned short tile[64][72];
  int c0 = blockIdx.x*64, r0 = blockIdx.y*64;
  #pragma unroll
  for (int i=0;i<16;++i){
    int idx = i*256 + threadIdx.x; int r = idx>>6, c = idx&63;
    tile[r][c] = src[(size_t)(r0+r)*C + c0 + c];
  }
  __syncthreads();
  #pragma unroll
  for (int i=0;i<16;++i){
    int idx = i*256 + threadIdx.x; int r = idx>>6, c = idx&63;
    dst[(size_t)(c0+r)*R + r0 + c] = tile[c][r];
  }
}

// ---------------- bf16 GEMM: C(M,N) = A(M,K) * BT(N,K)^T --------------------
// 128x128 tile, BK=64, 256 thr (4 waves 2x2 of 64x64 = 2x2 of 32x32 MFMA),
// global_load_lds 16B, 16B-chunk XOR swizzle to break bank conflicts.
// MODE 0: cols<2048 -> fp32 qk buffer; <4096 -> bf16 v; else bf16 g.
// MODE 1: fp32 -> out.
template<int MODE>
__global__ __launch_bounds__(256) void k_gemm_bt(
    const unsigned short* __restrict__ A, const unsigned short* __restrict__ BT,
    int M, int N, int K,
    float* __restrict__ out_f32, unsigned short* __restrict__ out_v,
    unsigned short* __restrict__ out_g)
{
  __shared__ __align__(16) short As[128*64];
  __shared__ __align__(16) short Bs[128*64];
  int bn = blockIdx.x*128, bm = blockIdx.y*128;
  int tid = threadIdx.x;
  int w = tid>>6, l = tid&63;
  int wr = w>>1, wc = w&1;
  int lrow = l&31, lhi = l>>5;
  floatx16 acc[2][2];
  #pragma unroll
  for (int a=0;a<2;++a)
    #pragma unroll
    for (int b=0;b<2;++b)
      #pragma unroll
      for (int j=0;j<16;++j) acc[a][b][j]=0.f;

  for (int k0=0; k0<K; k0+=64){
    __syncthreads();
    #pragma unroll
    for (int i=0;i<4;++i){
      int idx = i*256 + tid; int r = idx>>3, c = idx&7;
      int cs = c ^ (r&7);
      async_cp16((const char*)A  + ((size_t)(bm+r)*K + k0 + cs*8)*2, &As[idx*8]);
      async_cp16((const char*)BT + ((size_t)(bn+r)*K + k0 + cs*8)*2, &Bs[idx*8]);
    }
    __syncthreads();
    #pragma unroll
    for (int kc=0;kc<4;++kc){
      short8 af[2], bf[2];
      #pragma unroll
      for (int tm=0;tm<2;++tm){
        int row = wr*64 + tm*32 + lrow;
        int pos = (2*kc + lhi) ^ (row&7);
        af[tm] = *(const short8*)&As[row*64 + pos*8];
      }
      #pragma unroll
      for (int tn=0;tn<2;++tn){
        int row = wc*64 + tn*32 + lrow;
        int pos = (2*kc + lhi) ^ (row&7);
        bf[tn] = *(const short8*)&Bs[row*64 + pos*8];
      }
      #pragma unroll
      for (int tm=0;tm<2;++tm)
        #pragma unroll
        for (int tn=0;tn<2;++tn)
          acc[tm][tn] = __builtin_amdgcn_mfma_f32_32x32x16_bf16(af[tm], bf[tn], acc[tm][tn], 0,0,0);
    }
  }
  #pragma unroll
  for (int tm=0;tm<2;++tm)
    #pragma unroll
    for (int tn=0;tn<2;++tn)
      #pragma unroll
      for (int r=0;r<16;++r){
        int row = bm + wr*64 + tm*32 + (r&3) + 8*(r>>2) + 4*lhi;
        int col = bn + wc*64 + tn*32 + lrow;
        float v = acc[tm][tn][r];
        if (MODE==0){
          if (col < 2048)      out_f32[(size_t)row*2048 + col] = v;
          else if (col < 4096) out_v[(size_t)row*2048 + (col-2048)] = f2bf(v);
          else                 out_g[(size_t)row*2048 + (col-4096)] = f2bf(v);
        } else {
          out_f32[(size_t)row*N + col] = v;
        }
      }
}

// ---------------- rotary (theta shift) + k scaling, fp32 -> bf16 ------------
__global__ void k_rotary(const float* __restrict__ qk, const float* __restrict__ sinp,
                         const float* __restrict__ cosp,
                         unsigned short* __restrict__ qrp, unsigned short* __restrict__ krp)
{
  int tid = blockIdx.x*blockDim.x + threadIdx.x;   // T*1024 pair-units
  int t = tid >> 10, p = tid & 1023;
  bool isq = p < 512;
  int c = (isq ? p : p - 512)*2;
  int d = c & 127;
  const float* base = qk + (size_t)t*2048 + (isq ? 0 : 1024) + c;
  float f0 = base[0], f1 = base[1];
  float s0 = sinp[t*128 + d],   s1 = sinp[t*128 + d + 1];
  float c0 = cosp[t*128 + d],   c1 = cosp[t*128 + d + 1];
  float r0 = f0*c0 - f1*s0;
  float r1 = f1*c1 + f0*s1;
  if (!isq){ r0 *= 0.08838834764831845f; r1 *= 0.08838834764831845f; }  // KD^-0.5
  unsigned short* dst = (isq ? qrp : krp) + (size_t)t*1024 + c;
  dst[0] = f2bf(r0); dst[1] = f2bf(r1);
}

// ---------------- retention attention ---------------------------------------
// Grid: 512 blocks = 8 heads x 64 q-tiles(64 rows). 128 thr = 2 waves, each
// wave owns 32 q-rows x all 256 hd. Q frags in regs; K tile (32x128) and
// VT tile (256x32) async-staged to LDS with 16B XOR swizzle; S->P via
// wave-private LDS roundtrip; unnormalized O + den accumulated, divided at end.
__global__ __launch_bounds__(128, 2) void k_attn(
    const unsigned short* __restrict__ qr, const unsigned short* __restrict__ kr,
    const unsigned short* __restrict__ vT, unsigned short* __restrict__ o_out)
{
  __shared__ __align__(16) short Ks[32*128];    // 32 s-rows x 256B (16 chunks)
  __shared__ __align__(16) short Vs[256*32];    // 256 hd-rows x 64B (4 chunks)
  __shared__ __align__(16) short Ps[64*40];     // 64 rows x 80B (64B data + pad)
  int b = blockIdx.x;
  int head = b & 7;
  int u = b >> 3;
  int qt = (u < 32) ? u : 95 - u;   // pair long+short tiles on same CU slot
  int t0 = qt*64;
  int tid = threadIdx.x;
  int w = tid>>6, l = tid&63;
  int wm = w*32;
  int lrow = l&31, lhi = l>>5;

  float gamma = 1.f - exp2f(-5.f - (float)head);
  float L = log2f(gamma);                         // negative

  short8 qf[8];
  const unsigned short* qbase = qr + (size_t)(t0+wm+lrow)*1024 + head*128;
  #pragma unroll
  for (int kc=0;kc<8;++kc) qf[kc] = *(const short8*)(qbase + kc*16 + lhi*8);

  floatx16 o[8];
  #pragma unroll
  for (int i=0;i<8;++i)
    #pragma unroll
    for (int j=0;j<16;++j) o[i][j]=0.f;
  float den[16];
  #pragma unroll
  for (int r=0;r<16;++r) den[r]=0.f;
  float rowf[16];
  #pragma unroll
  for (int r=0;r<16;++r){
    int row = (r&3)+8*(r>>2)+4*lhi;
    rowf[r] = exp2f(L*(float)row);
  }
  float colf = exp2f(-L*(float)lrow);

  int dmax = (int)(40.0f/(-L));       // mask < 2^-40 beyond this: skip
  int s0s = t0 - dmax; if (s0s < 0) s0s = 0; s0s &= ~31;

  for (int s0 = s0s; s0 <= t0+32; s0 += 32){
    __syncthreads();
    #pragma unroll
    for (int i=0;i<4;++i){            // stage K: 8KB
      int idx = i*128 + tid; int r = idx>>4, c = idx&15;
      int cs = c ^ (r&15);
      async_cp16((const char*)kr + ((size_t)(s0+r)*1024 + head*128 + cs*8)*2, &Ks[idx*8]);
    }
    #pragma unroll
    for (int i=0;i<8;++i){            // stage VT: 16KB
      int idx = i*128 + tid; int r = idx>>2, c = idx&3;
      int cs = c ^ (r&3);
      async_cp16((const char*)vT + ((size_t)(head*256+r)*4096 + s0 + cs*8)*2, &Vs[idx*8]);
    }
    __syncthreads();

    floatx16 s;
    #pragma unroll
    for (int j=0;j<16;++j) s[j]=0.f;
    #pragma unroll
    for (int kc=0;kc<8;++kc){
      int pos = (2*kc + lhi) ^ (lrow&15);
      short8 bfr = *(const short8*)&Ks[lrow*128 + pos*8];
      s = __builtin_amdgcn_mfma_f32_32x32x16_bf16(qf[kc], bfr, s, 0,0,0);
    }

    float tf = exp2f(L*(float)(t0+wm-s0));
    bool diag = (s0 + 31 > t0 + wm);
    #pragma unroll
    for (int r=0;r<16;++r){
      int row = (r&3)+8*(r>>2)+4*lhi;
      float val = s[r]*(tf*rowf[r]*colf);
      if (diag){ if ((t0+wm+row) - (s0+lrow) < 0) val = 0.f; }
      den[r] += fabsf(val);
      Ps[(wm+row)*40 + lrow] = (short)f2bf(val);
    }
    // wave-private P: same wave wrote rows wm..wm+31, reads them back
    #pragma unroll
    for (int kc=0;kc<2;++kc){
      short8 pa = *(const short8*)&Ps[(wm+lrow)*40 + kc*16 + lhi*8];
      #pragma unroll
      for (int nt=0;nt<8;++nt){
        int vrow = nt*32 + lrow;
        int pos = (2*kc + lhi) ^ (vrow&3);
        short8 vb = *(const short8*)&Vs[vrow*32 + pos*8];
        o[nt] = __builtin_amdgcn_mfma_f32_32x32x16_bf16(pa, vb, o[nt], 0,0,0);
      }
    }
  }

  float scale[16];
  #pragma unroll
  for (int r=0;r<16;++r){
    float d = den[r];
    #pragma unroll
    for (int off=1; off<32; off<<=1) d += __shfl_xor(d, off, 64);
    scale[r] = 1.0f/fminf(fmaxf(d, 1.0f), 50000.0f);
  }
  #pragma unroll
  for (int nt=0;nt<8;++nt)
    #pragma unroll
    for (int r=0;r<16;++r){
      int row = (r&3)+8*(r>>2)+4*lhi;
      float v = o[nt][r]*scale[r];
      o_out[(size_t)(t0+wm+row)*2048 + head*256 + nt*32 + lrow] = f2bf(v);
    }
}

// ---------------- group RMS + SiLU gate -------------------------------------
__global__ __launch_bounds__(256) void k_rmsgate(const unsigned short* __restrict__ o_bf16,
    const unsigned short* __restrict__ g_bf16, unsigned short* __restrict__ gated)
{
  int t = blockIdx.x;
  int tid = threadIdx.x;
  size_t base = (size_t)t*2048 + tid*8;     // thread: 8 elems; 32 threads = one head group (256)
  short8 ov = *(const short8*)(o_bf16 + base);
  short8 gv = *(const short8*)(g_bf16 + base);
  float of[8], gf[8]; float ss = 0.f;
  #pragma unroll
  for (int j=0;j<8;++j){
    of[j]=bf2f((unsigned short)ov[j]);
    gf[j]=bf2f((unsigned short)gv[j]);
    ss += of[j]*of[j];
  }
  #pragma unroll
  for (int off=1; off<32; off<<=1) ss += __shfl_xor(ss, off, 64);
  float rms = rsqrtf(ss*(1.0f/256.0f) + 1e-6f);
  short8 outv;
  #pragma unroll
  for (int j=0;j<8;++j){
    float g = gf[j];
    float si = g / (1.0f + expf(-g));
    outv[j] = (short)f2bf(si * of[j] * rms);
  }
  *(short8*)(gated + base) = outv;
}

// ---------------------------------------------------------------------------
extern "C" void kernel_launch(void* const* d_in, const int* in_sizes, int n_in,
                              void* d_out, int out_size, void* d_ws, size_t ws_size,
                              hipStream_t stream)
{
  const float* x    = (const float*)d_in[0];
  const float* sinp = (const float*)d_in[1];
  const float* cosp = (const float*)d_in[2];
  // d_in[3] = inner_mask: intentionally unused (computed analytically)
  const float* Wq = (const float*)d_in[4];
  const float* Wk = (const float*)d_in[5];
  const float* Wv = (const float*)d_in[6];
  const float* Wg = (const float*)d_in[7];
  const float* Wo = (const float*)d_in[8];

  char* ws = (char*)d_ws;
  size_t off = 0;
  auto alloc = [&](size_t bytes)->char*{ char* p = ws + off; off += (bytes + 255) & ~(size_t)255; return p; };
  unsigned short* x_bf   = (unsigned short*)alloc((size_t)4096*1024*2);  // reused as qr
  unsigned short* WallT  = (unsigned short*)alloc((size_t)6144*1024*2);  // reused as kr
  float*          qk_f32 = (float*)         alloc((size_t)4096*2048*4);  // reused as o_bf + gated
  unsigned short* v_bf   = (unsigned short*)alloc((size_t)4096*2048*2);
  unsigned short* g_bf   = (unsigned short*)alloc((size_t)4096*2048*2);
  unsigned short* vT     = (unsigned short*)alloc((size_t)2048*4096*2);
  unsigned short* WoT    = (unsigned short*)alloc((size_t)1024*2048*2);
  unsigned short* qrp    = x_bf;                       // alias (x_bf dead after qkvg GEMM)
  unsigned short* krp    = WallT;                      // alias (WallT dead after qkvg GEMM)
  unsigned short* o_bf   = (unsigned short*)qk_f32;    // alias (qk_f32 dead after rotary)
  unsigned short* gated  = o_bf + (size_t)4096*2048;

  // prep
  k_cvt_x<<<4096, 256, 0, stream>>>(x, x_bf, 4096*1024/4);
  k_transpose_f2b<<<dim3(16,16), 256, 0, stream>>>(Wq, WallT,                  1024, 1024);
  k_transpose_f2b<<<dim3(16,16), 256, 0, stream>>>(Wk, WallT + 1024*1024,      1024, 1024);
  k_transpose_f2b<<<dim3(32,16), 256, 0, stream>>>(Wv, WallT + 2048*1024,      1024, 2048);
  k_transpose_f2b<<<dim3(32,16), 256, 0, stream>>>(Wg, WallT + (size_t)4096*1024, 1024, 2048);
  k_transpose_f2b<<<dim3(16,32), 256, 0, stream>>>(Wo, WoT,                    2048, 1024);

  // qkvg = x @ [Wq|Wk|Wv|Wg]
  k_gemm_bt<0><<<dim3(48,32), 256, 0, stream>>>(x_bf, WallT, 4096, 6144, 1024, qk_f32, v_bf, g_bf);

  // rotary + k-scaling -> bf16 (overwrites x_bf/WallT aliases)
  k_rotary<<<16384, 256, 0, stream>>>(qk_f32, sinp, cosp, qrp, krp);

  // V^T per head: (t, 2048) -> (2048, t)
  k_transpose_b2b<<<dim3(32,64), 256, 0, stream>>>(v_bf, vT, 4096, 2048);

  // retention attention -> o_bf (t, h*256+hd), den-normalized
  k_attn<<<512, 128, 0, stream>>>(qrp, krp, vT, o_bf);

  // RMS(group=256) + silu(g) gate -> gated bf16
  k_rmsgate<<<4096, 256, 0, stream>>>(o_bf, g_bf, gated);

  // out = gated @ Wo -> fp32 d_out
  k_gemm_bt<1><<<dim3(8,32), 256, 0, stream>>>(gated, WoT, 4096, 1024, 2048,
                                               (float*)d_out, nullptr, nullptr);

  (void)in_sizes; (void)n_in; (void)out_size; (void)ws_size;
}

// Round 2
// 1082.120 us; speedup vs baseline: 1.0340x; 1.0340x over previous
//
#include <hip/hip_runtime.h>

// ---------------------------------------------------------------------------
// MultiScaleRetention forward, MI355X/gfx950.  B=1,T=4096,E=1024,VD=2048,H=8.
// R2: barrier-free attention (K/V fragments straight from L2-resident global,
// wave-private P roundtrip only), 4 waves/block (qhalf x hdhalf), split-K
// out-GEMM with fp32 atomics, fused weight-transpose prep.
// ---------------------------------------------------------------------------

typedef __attribute__((ext_vector_type(8)))  short  short8;
typedef __attribute__((ext_vector_type(16))) float  floatx16;

__device__ inline unsigned short f2bf(float f){
  unsigned int u = __builtin_bit_cast(unsigned int, f);
  unsigned int r = (u + 0x7fffu + ((u >> 16) & 1u)) >> 16;   // RNE
  return (unsigned short)r;
}
__device__ inline float bf2f(unsigned short u){
  unsigned int x = ((unsigned int)u) << 16;
  return __builtin_bit_cast(float, x);
}
__device__ inline void async_cp16(const void* g, const void* l){
  __builtin_amdgcn_global_load_lds((const __attribute__((address_space(1))) void*)g,
                                   (__attribute__((address_space(3))) void*)l, 16, 0, 0);
}

// ---------------- x -> bf16 -------------------------------------------------
struct us4 { unsigned short a,b,c,d; };
__global__ void k_cvt_x(const float* __restrict__ x, unsigned short* __restrict__ xb, int n4){
  int i = blockIdx.x*blockDim.x + threadIdx.x;
  if (i >= n4) return;
  float4 v = ((const float4*)x)[i];
  us4 o = { f2bf(v.x), f2bf(v.y), f2bf(v.z), f2bf(v.w) };
  ((us4*)xb)[i] = o;
}

// ---------------- fused weight transposes (fp32 RxC -> bf16 CxR) ------------
struct WPrep  { const float* src; unsigned short* dst; int R; int C; int ntile; };
struct WPrepAll { WPrep w[5]; };
__global__ __launch_bounds__(256) void k_prep_w(WPrepAll a){
  __shared__ float tile[64][65];
  int b = blockIdx.x, i = 0;
  while (b >= a.w[i].ntile){ b -= a.w[i].ntile; ++i; }
  const float* src = a.w[i].src; unsigned short* dst = a.w[i].dst;
  int R = a.w[i].R, C = a.w[i].C;
  int tpr = C >> 6;
  int c0 = (b % tpr)*64, r0 = (b / tpr)*64;
  #pragma unroll
  for (int j=0;j<16;++j){
    int idx = j*256 + threadIdx.x; int r = idx>>6, c = idx&63;
    tile[r][c] = src[(size_t)(r0+r)*C + c0 + c];
  }
  __syncthreads();
  #pragma unroll
  for (int j=0;j<16;++j){
    int idx = j*256 + threadIdx.x; int r = idx>>6, c = idx&63;
    dst[(size_t)(c0+r)*R + r0 + c] = f2bf(tile[c][r]);
  }
}

// ---------------- bf16 (R,C) -> bf16 (C,R) transpose ------------------------
__global__ __launch_bounds__(256) void k_transpose_b2b(const unsigned short* __restrict__ src,
    unsigned short* __restrict__ dst, int R, int C){
  __shared__ unsigned short tile[64][72];
  int c0 = blockIdx.x*64, r0 = blockIdx.y*64;
  #pragma unroll
  for (int i=0;i<16;++i){
    int idx = i*256 + threadIdx.x; int r = idx>>6, c = idx&63;
    tile[r][c] = src[(size_t)(r0+r)*C + c0 + c];
  }
  __syncthreads();
  #pragma unroll
  for (int i=0;i<16;++i){
    int idx = i*256 + threadIdx.x; int r = idx>>6, c = idx&63;
    dst[(size_t)(c0+r)*R + r0 + c] = tile[c][r];
  }
}

// ---------------- bf16 GEMM: C(M,N) = A(M,K) * BT(N,K)^T --------------------
// 128x128 tile, BK=64, 256 thr. MODE 0: qkvg fanout epilogue. MODE 1: fp32
// atomicAdd epilogue (split-K via gridDim.z).
template<int MODE>
__global__ __launch_bounds__(256) void k_gemm_bt(
    const unsigned short* __restrict__ A, const unsigned short* __restrict__ BT,
    int M, int N, int K,
    float* __restrict__ out_f32, unsigned short* __restrict__ out_v,
    unsigned short* __restrict__ out_g)
{
  __shared__ __align__(16) short As[128*64];
  __shared__ __align__(16) short Bs[128*64];
  int bn = blockIdx.x*128, bm = blockIdx.y*128;
  int tid = threadIdx.x;
  int w = tid>>6, l = tid&63;
  int wr = w>>1, wc = w&1;
  int lrow = l&31, lhi = l>>5;
  floatx16 acc[2][2];
  #pragma unroll
  for (int a=0;a<2;++a)
    #pragma unroll
    for (int b=0;b<2;++b)
      #pragma unroll
      for (int j=0;j<16;++j) acc[a][b][j]=0.f;

  int kchunk = K / gridDim.z;
  int k_beg = blockIdx.z * kchunk;
  for (int k0=k_beg; k0<k_beg+kchunk; k0+=64){
    __syncthreads();
    #pragma unroll
    for (int i=0;i<4;++i){
      int idx = i*256 + tid; int r = idx>>3, c = idx&7;
      int cs = c ^ (r&7);
      async_cp16((const char*)A  + ((size_t)(bm+r)*K + k0 + cs*8)*2, &As[idx*8]);
      async_cp16((const char*)BT + ((size_t)(bn+r)*K + k0 + cs*8)*2, &Bs[idx*8]);
    }
    __syncthreads();
    #pragma unroll
    for (int kc=0;kc<4;++kc){
      short8 af[2], bf[2];
      #pragma unroll
      for (int tm=0;tm<2;++tm){
        int row = wr*64 + tm*32 + lrow;
        int pos = (2*kc + lhi) ^ (row&7);
        af[tm] = *(const short8*)&As[row*64 + pos*8];
      }
      #pragma unroll
      for (int tn=0;tn<2;++tn){
        int row = wc*64 + tn*32 + lrow;
        int pos = (2*kc + lhi) ^ (row&7);
        bf[tn] = *(const short8*)&Bs[row*64 + pos*8];
      }
      #pragma unroll
      for (int tm=0;tm<2;++tm)
        #pragma unroll
        for (int tn=0;tn<2;++tn)
          acc[tm][tn] = __builtin_amdgcn_mfma_f32_32x32x16_bf16(af[tm], bf[tn], acc[tm][tn], 0,0,0);
    }
  }
  #pragma unroll
  for (int tm=0;tm<2;++tm)
    #pragma unroll
    for (int tn=0;tn<2;++tn)
      #pragma unroll
      for (int r=0;r<16;++r){
        int row = bm + wr*64 + tm*32 + (r&3) + 8*(r>>2) + 4*lhi;
        int col = bn + wc*64 + tn*32 + lrow;
        float v = acc[tm][tn][r];
        if (MODE==0){
          if (col < 2048)      out_f32[(size_t)row*2048 + col] = v;
          else if (col < 4096) out_v[(size_t)row*2048 + (col-2048)] = f2bf(v);
          else                 out_g[(size_t)row*2048 + (col-4096)] = f2bf(v);
        } else {
          atomicAdd(&out_f32[(size_t)row*N + col], v);
        }
      }
}

// ---------------- rotary (theta shift) + k scaling, fp32 -> bf16 ------------
__global__ void k_rotary(const float* __restrict__ qk, const float* __restrict__ sinp,
                         const float* __restrict__ cosp,
                         unsigned short* __restrict__ qrp, unsigned short* __restrict__ krp)
{
  int tid = blockIdx.x*blockDim.x + threadIdx.x;   // T*1024 pair-units
  int t = tid >> 10, p = tid & 1023;
  bool isq = p < 512;
  int c = (isq ? p : p - 512)*2;
  int d = c & 127;
  const float* base = qk + (size_t)t*2048 + (isq ? 0 : 1024) + c;
  float f0 = base[0], f1 = base[1];
  float s0 = sinp[t*128 + d],   s1 = sinp[t*128 + d + 1];
  float c0 = cosp[t*128 + d],   c1 = cosp[t*128 + d + 1];
  float r0 = f0*c0 - f1*s0;
  float r1 = f1*c1 + f0*s1;
  if (!isq){ r0 *= 0.08838834764831845f; r1 *= 0.08838834764831845f; }  // KD^-0.5
  unsigned short* dst = (isq ? qrp : krp) + (size_t)t*1024 + c;
  dst[0] = f2bf(r0); dst[1] = f2bf(r1);
}

// ---------------- retention attention (barrier-free) ------------------------
// 512 blocks = 8 heads x 64 qtiles(64 rows), launched longest-first.
// 256 thr = 4 waves: wave = (qhalf, hdhalf). Each wave: 32 q-rows x 128 hd,
// loops over all its s-tiles (32 cols/iter). K and V MFMA fragments read
// directly from global (L2/L3-resident); only wave-private P LDS roundtrip
// (no barriers anywhere in the loop). Unnormalized O + den, divide at end.
__global__ __launch_bounds__(256, 2) void k_attn(
    const unsigned short* __restrict__ qr, const unsigned short* __restrict__ kr,
    const unsigned short* __restrict__ vT, unsigned short* __restrict__ o_out)
{
  __shared__ __align__(16) short Ps[4][32*40];   // per-wave 32 rows x 40 shorts
  int b = blockIdx.x;
  int head = b & 7;
  int qt = 63 - (b >> 3);                        // longest blocks first
  int tid = threadIdx.x;
  int w = tid>>6, l = tid&63;
  int qh = w>>1, hh = w&1;
  int lrow = l&31, lhi = l>>5;
  int tbase = qt*64 + qh*32;                     // wave's first q-row

  float gamma = 1.f - exp2f(-5.f - (float)head);
  float L = log2f(gamma);                        // negative

  short8 qf[8];
  const unsigned short* qbase = qr + (size_t)(tbase+lrow)*1024 + head*128 + lhi*8;
  #pragma unroll
  for (int kc=0;kc<8;++kc) qf[kc] = *(const short8*)(qbase + kc*16);

  floatx16 o[4];
  #pragma unroll
  for (int i=0;i<4;++i)
    #pragma unroll
    for (int j=0;j<16;++j) o[i][j]=0.f;
  float den[16];
  #pragma unroll
  for (int r=0;r<16;++r) den[r]=0.f;
  float rowf[16];
  #pragma unroll
  for (int r=0;r<16;++r){
    int row = (r&3)+8*(r>>2)+4*lhi;
    rowf[r] = exp2f(L*(float)row);
  }
  float colf = exp2f(-L*(float)lrow);

  int dmax = (int)(40.0f/(-L));                  // decay < 2^-40 beyond: skip
  int s_start = tbase - dmax; if (s_start < 0) s_start = 0; s_start &= ~31;

  short* myP = &Ps[w][0];
  const unsigned short* kb = kr + head*128 + lhi*8;
  const unsigned short* vb = vT + (size_t)(head*256 + hh*128)*4096 + lhi*8;

  for (int s0 = s_start; s0 <= tbase; s0 += 32){
    // --- QK^T : K fragments straight from global ---
    floatx16 s;
    #pragma unroll
    for (int j=0;j<16;++j) s[j]=0.f;
    const unsigned short* kp = kb + (size_t)(s0+lrow)*1024;
    #pragma unroll
    for (int kc=0;kc<8;++kc){
      short8 bfr = *(const short8*)(kp + kc*16);
      s = __builtin_amdgcn_mfma_f32_32x32x16_bf16(qf[kc], bfr, s, 0,0,0);
    }
    // --- decay mask + den + P (wave-private LDS, no barrier) ---
    float tf = exp2f(L*(float)(tbase - s0));
    bool diag = (s0 + 31 > tbase);
    #pragma unroll
    for (int r=0;r<16;++r){
      int row = (r&3)+8*(r>>2)+4*lhi;
      float val = s[r]*(tf*rowf[r]*colf);
      if (diag){ if (tbase+row < s0+lrow) val = 0.f; }
      den[r] += fabsf(val);
      myP[row*40 + lrow] = (short)f2bf(val);
    }
    short8 pa[2];
    #pragma unroll
    for (int kc=0;kc<2;++kc)
      pa[kc] = *(const short8*)&myP[lrow*40 + kc*16 + lhi*8];
    // --- PV : V fragments straight from global ---
    const unsigned short* vp = vb + s0;
    #pragma unroll
    for (int nt=0;nt<4;++nt){
      const unsigned short* vr = vp + (size_t)(nt*32+lrow)*4096;
      #pragma unroll
      for (int kc=0;kc<2;++kc){
        short8 vv = *(const short8*)(vr + kc*16);
        o[nt] = __builtin_amdgcn_mfma_f32_32x32x16_bf16(pa[kc], vv, o[nt], 0,0,0);
      }
    }
  }

  float scale[16];
  #pragma unroll
  for (int r=0;r<16;++r){
    float d = den[r];
    #pragma unroll
    for (int off=1; off<32; off<<=1) d += __shfl_xor(d, off, 64);
    scale[r] = 1.0f/fminf(fmaxf(d, 1.0f), 50000.0f);
  }
  #pragma unroll
  for (int nt=0;nt<4;++nt)
    #pragma unroll
    for (int r=0;r<16;++r){
      int row = (r&3)+8*(r>>2)+4*lhi;
      float v = o[nt][r]*scale[r];
      o_out[(size_t)(tbase+row)*2048 + head*256 + hh*128 + nt*32 + lrow] = f2bf(v);
    }
}

// ---------------- group RMS + SiLU gate -------------------------------------
__global__ __launch_bounds__(256) void k_rmsgate(const unsigned short* __restrict__ o_bf16,
    const unsigned short* __restrict__ g_bf16, unsigned short* __restrict__ gated)
{
  int t = blockIdx.x;
  int tid = threadIdx.x;
  size_t base = (size_t)t*2048 + tid*8;     // 32 threads = one head group (256)
  short8 ov = *(const short8*)(o_bf16 + base);
  short8 gv = *(const short8*)(g_bf16 + base);
  float of[8], gf[8]; float ss = 0.f;
  #pragma unroll
  for (int j=0;j<8;++j){
    of[j]=bf2f((unsigned short)ov[j]);
    gf[j]=bf2f((unsigned short)gv[j]);
    ss += of[j]*of[j];
  }
  #pragma unroll
  for (int off=1; off<32; off<<=1) ss += __shfl_xor(ss, off, 64);
  float rms = rsqrtf(ss*(1.0f/256.0f) + 1e-6f);
  short8 outv;
  #pragma unroll
  for (int j=0;j<8;++j){
    float g = gf[j];
    float si = g / (1.0f + expf(-g));
    outv[j] = (short)f2bf(si * of[j] * rms);
  }
  *(short8*)(gated + base) = outv;
}

// ---------------------------------------------------------------------------
extern "C" void kernel_launch(void* const* d_in, const int* in_sizes, int n_in,
                              void* d_out, int out_size, void* d_ws, size_t ws_size,
                              hipStream_t stream)
{
  const float* x    = (const float*)d_in[0];
  const float* sinp = (const float*)d_in[1];
  const float* cosp = (const float*)d_in[2];
  // d_in[3] = inner_mask: intentionally unused (computed analytically)
  const float* Wq = (const float*)d_in[4];
  const float* Wk = (const float*)d_in[5];
  const float* Wv = (const float*)d_in[6];
  const float* Wg = (const float*)d_in[7];
  const float* Wo = (const float*)d_in[8];

  char* ws = (char*)d_ws;
  size_t off = 0;
  auto alloc = [&](size_t bytes)->char*{ char* p = ws + off; off += (bytes + 255) & ~(size_t)255; return p; };
  unsigned short* x_bf   = (unsigned short*)alloc((size_t)4096*1024*2);  // reused as qr
  unsigned short* WallT  = (unsigned short*)alloc((size_t)6144*1024*2);  // reused as kr
  float*          qk_f32 = (float*)         alloc((size_t)4096*2048*4);  // reused as o_bf + gated
  unsigned short* v_bf   = (unsigned short*)alloc((size_t)4096*2048*2);
  unsigned short* g_bf   = (unsigned short*)alloc((size_t)4096*2048*2);
  unsigned short* vT     = (unsigned short*)alloc((size_t)2048*4096*2);
  unsigned short* WoT    = (unsigned short*)alloc((size_t)1024*2048*2);
  unsigned short* qrp    = x_bf;                       // alias (x_bf dead after qkvg GEMM)
  unsigned short* krp    = WallT;                      // alias (WallT dead after qkvg GEMM)
  unsigned short* o_bf   = (unsigned short*)qk_f32;    // alias (qk_f32 dead after rotary)
  unsigned short* gated  = o_bf + (size_t)4096*2048;

  // d_out is poisoned 0xAA; final GEMM uses atomic split-K -> zero it early
  hipMemsetAsync(d_out, 0, (size_t)4096*1024*4, stream);

  // prep
  k_cvt_x<<<4096, 256, 0, stream>>>(x, x_bf, 4096*1024/4);
  WPrepAll pa;
  pa.w[0] = { Wq, WallT,                        1024, 1024, 256 };
  pa.w[1] = { Wk, WallT + 1024*1024,            1024, 1024, 256 };
  pa.w[2] = { Wv, WallT + 2048*1024,            1024, 2048, 512 };
  pa.w[3] = { Wg, WallT + (size_t)4096*1024,    1024, 2048, 512 };
  pa.w[4] = { Wo, WoT,                          2048, 1024, 512 };
  k_prep_w<<<2048, 256, 0, stream>>>(pa);

  // qkvg = x @ [Wq|Wk|Wv|Wg]
  k_gemm_bt<0><<<dim3(48,32,1), 256, 0, stream>>>(x_bf, WallT, 4096, 6144, 1024, qk_f32, v_bf, g_bf);

  // rotary + k-scaling -> bf16 (overwrites x_bf/WallT aliases)
  k_rotary<<<16384, 256, 0, stream>>>(qk_f32, sinp, cosp, qrp, krp);

  // V^T per head: (t, 2048) -> (2048, t)
  k_transpose_b2b<<<dim3(32,64), 256, 0, stream>>>(v_bf, vT, 4096, 2048);

  // retention attention -> o_bf (t, h*256+hd), den-normalized
  k_attn<<<512, 256, 0, stream>>>(qrp, krp, vT, o_bf);

  // RMS(group=256) + silu(g) gate -> gated bf16
  k_rmsgate<<<4096, 256, 0, stream>>>(o_bf, g_bf, gated);

  // out = gated @ Wo -> fp32 d_out (split-K=2, atomic accumulate)
  k_gemm_bt<1><<<dim3(8,32,2), 256, 0, stream>>>(gated, WoT, 4096, 1024, 2048,
                                                 (float*)d_out, nullptr, nullptr);

  (void)in_sizes; (void)n_in; (void)out_size; (void)ws_size;
}